// Round 1
// baseline (328.962 us; speedup 1.0000x reference)
//
#include <hip/hip_runtime.h>
#include <hip/hip_bf16.h>
#include <stdint.h>

#define B_    2
#define S_    4096
#define DM_   2048
#define H_    16
#define D_    128
#define M_TOT (B_ * S_)     // 8192
#define N_TOT (3 * DM_)     // 6144
#define K_TOT DM_           // 2048

typedef __attribute__((ext_vector_type(8))) short  short8;
typedef __attribute__((ext_vector_type(4))) float  f32x4;

__device__ __forceinline__ unsigned short f2bf(float f) {
    union { float f; unsigned u; } u; u.f = f;
    unsigned r = u.u + 0x7fffu + ((u.u >> 16) & 1u);
    return (unsigned short)(r >> 16);
}
__device__ __forceinline__ float bf2f(unsigned short s) {
    union { unsigned u; float f; } u; u.u = ((unsigned)s) << 16;
    return u.f;
}

__device__ __forceinline__ void gload_lds16(const void* g, void* l) {
    __builtin_amdgcn_global_load_lds(
        (const __attribute__((address_space(1))) void*)g,
        (__attribute__((address_space(3))) void*)l,
        16, 0, 0);
}

// ---------------- cast fp32 -> bf16 (vectorized) ----------------
__global__ void cast_f32_bf16(const float* __restrict__ src,
                              unsigned short* __restrict__ dst, int n4) {
    int i = blockIdx.x * blockDim.x + threadIdx.x;
    int stride = gridDim.x * blockDim.x;
    for (; i < n4; i += stride) {
        float4 v = ((const float4*)src)[i];
        ushort4 o;
        o.x = f2bf(v.x); o.y = f2bf(v.y); o.z = f2bf(v.z); o.w = f2bf(v.w);
        ((ushort4*)dst)[i] = o;
    }
}

// ---------------- QKV projection GEMM ----------------
// C[M][N] = A[M][K] * B[N][K]^T  (+ bias per column section), all bf16 in, bf16 out
#define BM 128
#define BN 128
#define BK 64

__global__ __launch_bounds__(256, 2) void gemm_qkv(
    const unsigned short* __restrict__ A,   // [M_TOT][K_TOT] bf16
    const unsigned short* __restrict__ Bm,  // [N_TOT][K_TOT] bf16 (Wq;Wk;Wv)
    const float* __restrict__ bq, const float* __restrict__ bk,
    const float* __restrict__ bv,
    unsigned short* __restrict__ C)         // [M_TOT][N_TOT] bf16
{
    __shared__ __align__(16) unsigned short As[BM * BK]; // 16 KB
    __shared__ __align__(16) unsigned short Bs[BN * BK]; // 16 KB

    const int nwg = gridDim.x;              // 3072, divisible by 8
    const int cpx = nwg >> 3;
    const int bid = blockIdx.x;
    const int swz = (bid & 7) * cpx + (bid >> 3);   // XCD-contiguous chunks
    const int ntile = N_TOT / BN;           // 48
    const int tm = swz / ntile;
    const int tn = swz % ntile;

    const int tid  = threadIdx.x;
    const int w    = tid >> 6;
    const int lane = tid & 63;
    const int wr   = w >> 1, wc = w & 1;    // 2x2 wave grid, each 64x64

    f32x4 acc[4][4] = {};

    // staging: chunk c = w*4+j covers rows [c*8, c*8+8), lane covers 8 bf16
    const int r0  = w * 32 + (lane >> 3);
    const int kc0 = (lane & 7) * 8;
    const unsigned short* aSrc = A  + (size_t)(tm * BM + r0) * K_TOT + kc0;
    const unsigned short* bSrc = Bm + (size_t)(tn * BN + r0) * K_TOT + kc0;

    for (int k0 = 0; k0 < K_TOT; k0 += BK) {
        __syncthreads();   // previous compute done before overwrite
#pragma unroll
        for (int j = 0; j < 4; ++j) {
            gload_lds16(aSrc + (size_t)(j * 8) * K_TOT + k0, &As[(w * 4 + j) * 512]);
            gload_lds16(bSrc + (size_t)(j * 8) * K_TOT + k0, &Bs[(w * 4 + j) * 512]);
        }
        __syncthreads();   // drains vmcnt -> staged tiles visible

#pragma unroll
        for (int kk = 0; kk < BK; kk += 32) {
            short8 af[4], bf[4];
#pragma unroll
            for (int m = 0; m < 4; ++m)
                af[m] = *(const short8*)&As[(wr * 64 + m * 16 + (lane & 15)) * BK + kk + (lane >> 4) * 8];
#pragma unroll
            for (int n = 0; n < 4; ++n)
                bf[n] = *(const short8*)&Bs[(wc * 64 + n * 16 + (lane & 15)) * BK + kk + (lane >> 4) * 8];
#pragma unroll
            for (int m = 0; m < 4; ++m)
#pragma unroll
                for (int n = 0; n < 4; ++n)
                    acc[m][n] = __builtin_amdgcn_mfma_f32_16x16x32_bf16(af[m], bf[n], acc[m][n], 0, 0, 0);
        }
    }

    // epilogue: bias + bf16 store.  C/D layout: col = lane&15, row = (lane>>4)*4 + r
    const int colBase = tn * BN + wc * 64;
    const float* bias = (colBase < 2048) ? bq : (colBase < 4096) ? bk : bv;
    const int rowBase = tm * BM + wr * 64;
#pragma unroll
    for (int n = 0; n < 4; ++n) {
        const int col  = colBase + n * 16 + (lane & 15);
        const float bval = bias[col & 2047];
#pragma unroll
        for (int m = 0; m < 4; ++m) {
#pragma unroll
            for (int r = 0; r < 4; ++r) {
                const int row = rowBase + m * 16 + (lane >> 4) * 4 + r;
                C[(size_t)row * N_TOT + col] = f2bf(acc[m][n][r] + bval);
            }
        }
    }
}

// ---------------- per-position heads-attention ----------------
// one block (256 thr) per position; QKV row = [Q(2048) K(2048) V(2048)] bf16
#define LSTR 132   // padded fp32 row stride (breaks stride-128 bank conflicts)

__global__ __launch_bounds__(256) void attn_kernel(
    const unsigned short* __restrict__ QKV,  // [M_TOT][N_TOT] bf16
    float* __restrict__ out)                 // [B][S][DM] fp32, scattered layout
{
    __shared__ __align__(16) float Qs[H_ * LSTR];
    __shared__ __align__(16) float Ks[H_ * LSTR];
    __shared__ __align__(16) float Vs[H_ * LSTR];

    const int pos = blockIdx.x;          // b*S + s
    const int b   = pos >> 12;
    const int s   = pos & 4095;
    const int tid = threadIdx.x;
    const int lane = tid & 63;
    const unsigned short* row = QKV + (size_t)pos * N_TOT;

    // load + convert: thread handles 8 contiguous elems of each of Q,K,V
    {
        const int r  = tid >> 4;          // head index 0..15
        const int d0 = (tid & 15) * 8;
        short8 q = *(const short8*)(row +        r * 128 + d0);
        short8 k = *(const short8*)(row + 2048 + r * 128 + d0);
        short8 v = *(const short8*)(row + 4096 + r * 128 + d0);
#pragma unroll
        for (int j = 0; j < 8; ++j) {
            Qs[r * LSTR + d0 + j] = bf2f((unsigned short)q[j]);
            Ks[r * LSTR + d0 + j] = bf2f((unsigned short)k[j]);
            Vs[r * LSTR + d0 + j] = bf2f((unsigned short)v[j]);
        }
    }
    __syncthreads();

    // scores: thread (h = tid/16, t = tid%16)
    const int h = tid >> 4;
    const int t = tid & 15;
    float sc = 0.f;
    {
        const float* qp = &Qs[h * LSTR];
        const float* kp = &Ks[t * LSTR];
#pragma unroll
        for (int d = 0; d < 128; d += 4) {
            float4 qv = *(const float4*)(qp + d);
            float4 kv = *(const float4*)(kp + d);
            sc += qv.x * kv.x + qv.y * kv.y + qv.z * kv.z + qv.w * kv.w;
        }
    }
    sc *= 0.08838834764831845f;   // 1/sqrt(128)

    // softmax over t: lanes differing in bits 0..3 share the h-group
    float mx = sc;
#pragma unroll
    for (int o = 1; o < 16; o <<= 1) mx = fmaxf(mx, __shfl_xor(mx, o, 64));
    float e = __expf(sc - mx);
    float sm = e;
#pragma unroll
    for (int o = 1; o < 16; o <<= 1) sm += __shfl_xor(sm, o, 64);
    const float attn = e / sm;

    // out[h][d], this thread owns d in [t*8, t*8+8)
    float o8[8] = {0.f,0.f,0.f,0.f,0.f,0.f,0.f,0.f};
#pragma unroll
    for (int tt = 0; tt < 16; ++tt) {
        const float a = __shfl(attn, (lane & 48) | tt, 64);
        const float* vp = &Vs[tt * LSTR + t * 8];
        float4 v0 = *(const float4*)(vp);
        float4 v1 = *(const float4*)(vp + 4);
        o8[0] += a * v0.x; o8[1] += a * v0.y; o8[2] += a * v0.z; o8[3] += a * v0.w;
        o8[4] += a * v1.x; o8[5] += a * v1.y; o8[6] += a * v1.z; o8[7] += a * v1.w;
    }

    // scatter: out[b][h*256 + s/16][(s%16)*128 + d]
    const int orow = h * 256 + (s >> 4);
    const int ocol = (s & 15) * 128 + t * 8;
    float* op = out + ((size_t)b * S_ + orow) * DM_ + ocol;
    float4 w0 = { o8[0], o8[1], o8[2], o8[3] };
    float4 w1 = { o8[4], o8[5], o8[6], o8[7] };
    *(float4*)(op)     = w0;
    *(float4*)(op + 4) = w1;
}

// ---------------- launch ----------------
extern "C" void kernel_launch(void* const* d_in, const int* in_sizes, int n_in,
                              void* d_out, int out_size, void* d_ws, size_t ws_size,
                              hipStream_t stream) {
    const float* x  = (const float*)d_in[0];
    const float* Wq = (const float*)d_in[1];
    const float* bq = (const float*)d_in[2];
    const float* Wk = (const float*)d_in[3];
    const float* bk = (const float*)d_in[4];
    const float* Wv = (const float*)d_in[5];
    const float* bv = (const float*)d_in[6];
    float* out = (float*)d_out;

    char* ws = (char*)d_ws;
    unsigned short* xb  = (unsigned short*)ws;                          // 33,554,432 B
    unsigned short* Wb  = (unsigned short*)(ws + 33554432);             // 25,165,824 B
    unsigned short* qkv = (unsigned short*)(ws + 58720256);             // 100,663,296 B

    cast_f32_bf16<<<4096, 256, 0, stream>>>(x,  xb,              (M_TOT * K_TOT) / 4);
    cast_f32_bf16<<<2048, 256, 0, stream>>>(Wq, Wb,              (DM_ * DM_) / 4);
    cast_f32_bf16<<<2048, 256, 0, stream>>>(Wk, Wb + DM_ * DM_,  (DM_ * DM_) / 4);
    cast_f32_bf16<<<2048, 256, 0, stream>>>(Wv, Wb + 2 * DM_ * DM_, (DM_ * DM_) / 4);

    gemm_qkv<<<(M_TOT / BM) * (N_TOT / BN), 256, 0, stream>>>(xb, Wb, bq, bk, bv, qkv);

    attn_kernel<<<M_TOT, 256, 0, stream>>>(qkv, out);
}

// Round 2
// 299.322 us; speedup vs baseline: 1.0990x; 1.0990x over previous
//
#include <hip/hip_runtime.h>
#include <hip/hip_bf16.h>
#include <stdint.h>

#define B_    2
#define S_    4096
#define DM_   2048
#define H_    16
#define D_    128
#define M_TOT (B_ * S_)     // 8192
#define N_TOT (3 * DM_)     // 6144
#define K_TOT DM_           // 2048

typedef __attribute__((ext_vector_type(8))) short  short8;
typedef __attribute__((ext_vector_type(4))) float  f32x4;
typedef unsigned short ushort_t;

__device__ __forceinline__ unsigned short f2bf(float f) {
    union { float f; unsigned u; } u; u.f = f;
    unsigned r = u.u + 0x7fffu + ((u.u >> 16) & 1u);
    return (unsigned short)(r >> 16);
}
__device__ __forceinline__ float bf2f(unsigned short s) {
    union { unsigned u; float f; } u; u.u = ((unsigned)s) << 16;
    return u.f;
}

__device__ __forceinline__ void gload_lds16(const void* g, void* l) {
    __builtin_amdgcn_global_load_lds(
        (const __attribute__((address_space(1))) void*)g,
        (__attribute__((address_space(3))) void*)l,
        16, 0, 0);
}

__device__ __forceinline__ void wg_barrier() {
    asm volatile("" ::: "memory");
    __builtin_amdgcn_s_barrier();
    asm volatile("" ::: "memory");
}

// ---------------- cast fp32 -> bf16 (vectorized) ----------------
__global__ void cast_f32_bf16(const float* __restrict__ src,
                              unsigned short* __restrict__ dst, int n4) {
    int i = blockIdx.x * blockDim.x + threadIdx.x;
    int stride = gridDim.x * blockDim.x;
    for (; i < n4; i += stride) {
        float4 v = ((const float4*)src)[i];
        ushort4 o;
        o.x = f2bf(v.x); o.y = f2bf(v.y); o.z = f2bf(v.z); o.w = f2bf(v.w);
        ((ushort4*)dst)[i] = o;
    }
}

// ---------------- QKV projection GEMM: 256x256 tile, 8-phase schedule ----------
// C[M][N] = A[M][K] * B[N][K]^T (+bias), bf16 in, bf16 out.
// 512 thr = 8 waves (2M x 4N); per-wave output 128x64 (8x4 frags of 16x16).
// LDS: 2 buffers x (A[256][64] + B[256][64]) bf16 = 128 KiB, stored as
// 16x32-element subtiles (1024 B) with st_16x32 swizzle:
//   ushort_off(r,c) = (r*32 + c) ^ (((r>>3)&1)<<4)   within each subtile.
// global_load_lds writes subtiles linearly (lane L -> bytes L*16); the source
// address is inverse-swizzled so the READ-side swizzle sees consistent data.

#define BKT   64
#define NKT   (K_TOT / BKT)   // 32 K-tiles
#define ABUF  16384           // ushort offset of B-tile within a buffer
#define BUF1  32768           // ushort offset of buffer 1

#define LGKM0() do { asm volatile("s_waitcnt lgkmcnt(0)" ::: "memory"); \
                     __builtin_amdgcn_sched_barrier(0); } while (0)
#define VM8()   asm volatile("s_waitcnt vmcnt(8)" ::: "memory")
#define VM0()   asm volatile("s_waitcnt vmcnt(0)" ::: "memory")
#define NOSTAGE do {} while (0)
#define NOVM    do {} while (0)

// wave w stages rowblks {2w,2w+1} x colblks {0,1} of both A and B subtile grids
#define STAGE_KT(BO, K0) do {                                                   \
    const ushort_t* asrc = A  + (size_t)(tmRow + rb0 * 16 + rL) * K_TOT + (K0) + cSwzSt; \
    const ushort_t* bsrc = Bm + (size_t)(tnRow + rb0 * 16 + rL) * K_TOT + (K0) + cSwzSt; \
    gload_lds16(asrc,                 &lds[(BO) + (rb0 * 2 + 0) * 512]);        \
    gload_lds16(asrc + 32,            &lds[(BO) + (rb0 * 2 + 1) * 512]);        \
    gload_lds16(asrc + 16 * K_TOT,    &lds[(BO) + (rb0 * 2 + 2) * 512]);        \
    gload_lds16(asrc + 16 * K_TOT + 32, &lds[(BO) + (rb0 * 2 + 3) * 512]);      \
    gload_lds16(bsrc,                 &lds[(BO) + ABUF + (rb0 * 2 + 0) * 512]); \
    gload_lds16(bsrc + 32,            &lds[(BO) + ABUF + (rb0 * 2 + 1) * 512]); \
    gload_lds16(bsrc + 16 * K_TOT,    &lds[(BO) + ABUF + (rb0 * 2 + 2) * 512]); \
    gload_lds16(bsrc + 16 * K_TOT + 32, &lds[(BO) + ABUF + (rb0 * 2 + 3) * 512]); \
} while (0)

#define LOAD_A(I0, BO) do { _Pragma("unroll")                                   \
    for (int i = 0; i < 4; ++i) {                                               \
        a[i][0] = *(const short8*)&lds[(BO) + (wm * 8 + (I0) + i) * 1024 + innerRd]; \
        a[i][1] = *(const short8*)&lds[(BO) + (wm * 8 + (I0) + i) * 1024 + 512 + innerRd]; \
    } } while (0)

#define LOAD_B(N0, BO) do { _Pragma("unroll")                                   \
    for (int n = 0; n < 2; ++n) {                                               \
        b[(N0) + n][0] = *(const short8*)&lds[(BO) + ABUF + (wn * 4 + (N0) + n) * 1024 + innerRd]; \
        b[(N0) + n][1] = *(const short8*)&lds[(BO) + ABUF + (wn * 4 + (N0) + n) * 1024 + 512 + innerRd]; \
    } } while (0)

#define MFMA_Q(I0, N0) do { _Pragma("unroll")                                   \
    for (int i = 0; i < 4; ++i) { _Pragma("unroll")                             \
    for (int n = 0; n < 2; ++n) { _Pragma("unroll")                             \
    for (int ks = 0; ks < 2; ++ks)                                              \
        acc[(I0) + i][(N0) + n] = __builtin_amdgcn_mfma_f32_16x16x32_bf16(      \
            a[i][ks], b[(N0) + n][ks], acc[(I0) + i][(N0) + n], 0, 0, 0);       \
    } } } while (0)

// one K-tile = 4 phases; STAGE_STMT issues kt+2's 8 loads at P4 (buffer is
// read-complete after P3's trailing barrier); VM_STMT = vmcnt(8) keeps one
// K-tile of loads in flight (never drains to 0 in the main loop).
#define KTILE(BO, STAGE_STMT, VM_STMT) do {                                     \
    /* P1 */ LOAD_A(0, BO); LOAD_B(0, BO);                                      \
    wg_barrier(); LGKM0();                                                      \
    __builtin_amdgcn_s_setprio(1); MFMA_Q(0, 0); __builtin_amdgcn_s_setprio(0); \
    wg_barrier();                                                               \
    /* P2 */ LOAD_B(2, BO);                                                     \
    wg_barrier(); LGKM0();                                                      \
    __builtin_amdgcn_s_setprio(1); MFMA_Q(0, 2); __builtin_amdgcn_s_setprio(0); \
    wg_barrier();                                                               \
    /* P3 */ LOAD_A(4, BO);                                                     \
    wg_barrier(); LGKM0();                                                      \
    __builtin_amdgcn_s_setprio(1); MFMA_Q(4, 0); __builtin_amdgcn_s_setprio(0); \
    wg_barrier();                                                               \
    /* P4 */ STAGE_STMT;                                                        \
    wg_barrier();                                                               \
    __builtin_amdgcn_s_setprio(1); MFMA_Q(4, 2); __builtin_amdgcn_s_setprio(0); \
    VM_STMT;                                                                    \
    wg_barrier();                                                               \
} while (0)

__global__ __launch_bounds__(512, 2) void gemm_qkv(
    const ushort_t* __restrict__ A,   // [M_TOT][K_TOT] bf16
    const ushort_t* __restrict__ Bm,  // [N_TOT][K_TOT] bf16 (Wq;Wk;Wv)
    const float* __restrict__ bq, const float* __restrict__ bk,
    const float* __restrict__ bv,
    ushort_t* __restrict__ C)         // [M_TOT][N_TOT] bf16
{
    __shared__ __align__(16) ushort_t lds[65536];   // 128 KiB

    // XCD-aware bijective swizzle (768 % 8 == 0)
    const int nwg = gridDim.x;                  // 768
    const int cpx = nwg >> 3;                   // 96
    const int bid = blockIdx.x;
    const int swz = (bid & 7) * cpx + (bid >> 3);
    const int ntile = N_TOT / 256;              // 24
    const int tm = swz / ntile;
    const int tn = swz % ntile;
    const int tmRow = tm * 256, tnRow = tn * 256;

    const int tid  = threadIdx.x;
    const int w    = tid >> 6;
    const int lane = tid & 63;
    const int wm   = w >> 2, wn = w & 3;        // 2 x 4 wave grid
    const int rb0  = 2 * w;                     // staging rowblk base

    // staging source (inverse-swizzle): lane L -> row L>>2, col ((L&3)*8)^((L>>5)<<4)
    const int rL     = lane >> 2;
    const int cSwzSt = ((lane & 3) * 8) ^ (((lane >> 5) & 1) << 4);
    // ds_read fragment offset within a subtile (swizzled)
    const int rA      = lane & 15;
    const int innerRd = (rA * 32 + (lane >> 4) * 8) ^ (((rA >> 3) & 1) << 4);

    f32x4  acc[8][4] = {};
    short8 a[4][2], b[4][2];

    // prologue: K-tiles 0 -> buf0, 1 -> buf1; wait until kt0 landed (8 in flight)
    STAGE_KT(0, 0);
    STAGE_KT(BUF1, BKT);
    VM8();
    wg_barrier();

    // main loop: 15 iterations, kt = 0..29; stages kt+2 / kt+3
    for (int k0 = 0; k0 < (NKT - 2) * BKT; k0 += 2 * BKT) {
        KTILE(0,    STAGE_KT(0,    k0 + 2 * BKT), VM8());
        KTILE(BUF1, STAGE_KT(BUF1, k0 + 3 * BKT), VM8());
    }
    // epilogue K-tiles 30 (buf0), 31 (buf1): everything resident, read-only
    VM0();
    wg_barrier();
    KTILE(0,    NOSTAGE, NOVM);
    KTILE(BUF1, NOSTAGE, NOVM);

    // C-write: col = base + n*16 + (lane&15); row = base + i*16 + (lane>>4)*4 + r
    const int colBase = tnRow + wn * 64;
    const float* bias = (colBase < 2048) ? bq : (colBase < 4096) ? bk : bv;
    const int rowBase = tmRow + wm * 128;
#pragma unroll
    for (int n = 0; n < 4; ++n) {
        const int col = colBase + n * 16 + (lane & 15);
        const float bval = bias[col & 2047];
#pragma unroll
        for (int i = 0; i < 8; ++i) {
#pragma unroll
            for (int r = 0; r < 4; ++r) {
                const int row = rowBase + i * 16 + (lane >> 4) * 4 + r;
                C[(size_t)row * N_TOT + col] = f2bf(acc[i][n][r] + bval);
            }
        }
    }
}

// ---------------- per-position heads-attention ----------------
#define LSTR 132   // padded fp32 row stride (breaks stride-128 bank conflicts)

__global__ __launch_bounds__(256) void attn_kernel(
    const ushort_t* __restrict__ QKV,  // [M_TOT][N_TOT] bf16
    float* __restrict__ out)           // [B][S][DM] fp32, scattered layout
{
    __shared__ __align__(16) float Qs[H_ * LSTR];
    __shared__ __align__(16) float Ks[H_ * LSTR];
    __shared__ __align__(16) float Vs[H_ * LSTR];

    const int pos = blockIdx.x;
    const int b   = pos >> 12;
    const int s   = pos & 4095;
    const int tid = threadIdx.x;
    const int lane = tid & 63;
    const ushort_t* row = QKV + (size_t)pos * N_TOT;

    {
        const int r  = tid >> 4;
        const int d0 = (tid & 15) * 8;
        short8 q = *(const short8*)(row +        r * 128 + d0);
        short8 k = *(const short8*)(row + 2048 + r * 128 + d0);
        short8 v = *(const short8*)(row + 4096 + r * 128 + d0);
#pragma unroll
        for (int j = 0; j < 8; ++j) {
            Qs[r * LSTR + d0 + j] = bf2f((unsigned short)q[j]);
            Ks[r * LSTR + d0 + j] = bf2f((unsigned short)k[j]);
            Vs[r * LSTR + d0 + j] = bf2f((unsigned short)v[j]);
        }
    }
    __syncthreads();

    const int h = tid >> 4;
    const int t = tid & 15;
    float sc = 0.f;
    {
        const float* qp = &Qs[h * LSTR];
        const float* kp = &Ks[t * LSTR];
#pragma unroll
        for (int d = 0; d < 128; d += 4) {
            float4 qv = *(const float4*)(qp + d);
            float4 kv = *(const float4*)(kp + d);
            sc += qv.x * kv.x + qv.y * kv.y + qv.z * kv.z + qv.w * kv.w;
        }
    }
    sc *= 0.08838834764831845f;   // 1/sqrt(128)

    float mx = sc;
#pragma unroll
    for (int o = 1; o < 16; o <<= 1) mx = fmaxf(mx, __shfl_xor(mx, o, 64));
    float e = __expf(sc - mx);
    float sm = e;
#pragma unroll
    for (int o = 1; o < 16; o <<= 1) sm += __shfl_xor(sm, o, 64);
    const float attn = e / sm;

    float o8[8] = {0.f, 0.f, 0.f, 0.f, 0.f, 0.f, 0.f, 0.f};
#pragma unroll
    for (int tt = 0; tt < 16; ++tt) {
        const float aw = __shfl(attn, (lane & 48) | tt, 64);
        const float* vp = &Vs[tt * LSTR + t * 8];
        float4 v0 = *(const float4*)(vp);
        float4 v1 = *(const float4*)(vp + 4);
        o8[0] += aw * v0.x; o8[1] += aw * v0.y; o8[2] += aw * v0.z; o8[3] += aw * v0.w;
        o8[4] += aw * v1.x; o8[5] += aw * v1.y; o8[6] += aw * v1.z; o8[7] += aw * v1.w;
    }

    const int orow = h * 256 + (s >> 4);
    const int ocol = (s & 15) * 128 + t * 8;
    float* op = out + ((size_t)b * S_ + orow) * DM_ + ocol;
    float4 w0 = { o8[0], o8[1], o8[2], o8[3] };
    float4 w1 = { o8[4], o8[5], o8[6], o8[7] };
    *(float4*)(op)     = w0;
    *(float4*)(op + 4) = w1;
}

// ---------------- launch ----------------
extern "C" void kernel_launch(void* const* d_in, const int* in_sizes, int n_in,
                              void* d_out, int out_size, void* d_ws, size_t ws_size,
                              hipStream_t stream) {
    const float* x  = (const float*)d_in[0];
    const float* Wq = (const float*)d_in[1];
    const float* bq = (const float*)d_in[2];
    const float* Wk = (const float*)d_in[3];
    const float* bk = (const float*)d_in[4];
    const float* Wv = (const float*)d_in[5];
    const float* bv = (const float*)d_in[6];
    float* out = (float*)d_out;

    char* ws = (char*)d_ws;
    unsigned short* xb  = (unsigned short*)ws;                       // 33,554,432 B
    unsigned short* Wb  = (unsigned short*)(ws + 33554432);          // 25,165,824 B
    unsigned short* qkv = (unsigned short*)(ws + 58720256);          // 100,663,296 B

    cast_f32_bf16<<<4096, 256, 0, stream>>>(x,  xb,                 (M_TOT * K_TOT) / 4);
    cast_f32_bf16<<<2048, 256, 0, stream>>>(Wq, Wb,                 (DM_ * DM_) / 4);
    cast_f32_bf16<<<2048, 256, 0, stream>>>(Wk, Wb + DM_ * DM_,     (DM_ * DM_) / 4);
    cast_f32_bf16<<<2048, 256, 0, stream>>>(Wv, Wb + 2 * DM_ * DM_, (DM_ * DM_) / 4);

    gemm_qkv<<<(M_TOT / 256) * (N_TOT / 256), 512, 0, stream>>>(xb, Wb, bq, bk, bv, qkv);

    attn_kernel<<<M_TOT, 256, 0, stream>>>(qkv, out);
}